// Round 1
// baseline (527.988 us; speedup 1.0000x reference)
//
#include <hip/hip_runtime.h>
#include <hip/hip_bf16.h>

typedef __attribute__((ext_vector_type(8))) short short8;
typedef __attribute__((ext_vector_type(4))) float f32x4;

#define BN_EPS 1e-5f
#define MROWS 4096
#define CDIM 2048

__device__ __forceinline__ void gload_lds16(const void* g, void* l) {
  __builtin_amdgcn_global_load_lds(
      (const __attribute__((address_space(1))) void*)g,
      (__attribute__((address_space(3))) void*)l, 16, 0, 0);
}

// ---------------------------------------------------------------------------
// fp32 -> bf16 conversion (vectorized float4 -> ushort4)
// ---------------------------------------------------------------------------
__global__ __launch_bounds__(256) void cvt_f32_bf16(const float* __restrict__ in,
                                                    unsigned short* __restrict__ out,
                                                    int n4) {
  int idx = blockIdx.x * blockDim.x + threadIdx.x;
  int stride = gridDim.x * blockDim.x;
  for (int i = idx; i < n4; i += stride) {
    float4 vv = ((const float4*)in)[i];
    __hip_bfloat16 h0 = __float2bfloat16(vv.x);
    __hip_bfloat16 h1 = __float2bfloat16(vv.y);
    __hip_bfloat16 h2 = __float2bfloat16(vv.z);
    __hip_bfloat16 h3 = __float2bfloat16(vv.w);
    ushort4 o;
    o.x = *(unsigned short*)&h0;
    o.y = *(unsigned short*)&h1;
    o.z = *(unsigned short*)&h2;
    o.w = *(unsigned short*)&h3;
    ((ushort4*)out)[i] = o;
  }
}

// ---------------------------------------------------------------------------
// GEMM: out[h][m][d] = relu( (sum_c A[h][m][c] * W[h][d][c]) * scale + shift )
// A: bf16 [.. , M, C] (head stride a_hstride elems; 0 => shared across heads)
// W: bf16 [H][C][C]  row d holds K-contiguous weights (B^T layout)
// 128x128 tile, BK=32, 4 waves (2x2), mfma_f32_16x16x32_bf16.
// ---------------------------------------------------------------------------
__global__ __launch_bounds__(256) void gemm_bn_relu(
    const __hip_bfloat16* __restrict__ A, long long a_hstride,
    const __hip_bfloat16* __restrict__ W,
    const float* __restrict__ gp, const float* __restrict__ bp,
    const float* __restrict__ mp, const float* __restrict__ vp,
    __hip_bfloat16* __restrict__ out)
{
  __shared__ __hip_bfloat16 As[128 * 32];
  __shared__ __hip_bfloat16 Bs[128 * 32];

  const int tid  = threadIdx.x;
  const int wave = tid >> 6;
  const int lane = tid & 63;
  const int h    = blockIdx.y;
  const int mt   = blockIdx.x >> 4;   // 32 m-tiles
  const int nt   = blockIdx.x & 15;   // 16 n-tiles

  const __hip_bfloat16* Ah = A + (size_t)h * (size_t)a_hstride;
  const __hip_bfloat16* Wh = W + (size_t)h * CDIM * CDIM;

  // staging: per wave 2 insts for A (16 rows each) + 2 for B.
  // lane -> (row = lane/4, 16B chunk = lane%4); LDS dest is linear (lane*16).
  const __hip_bfloat16* aSrc =
      Ah + (size_t)(mt * 128 + wave * 32 + (lane >> 2)) * CDIM + (lane & 3) * 8;
  const __hip_bfloat16* bSrc =
      Wh + (size_t)(nt * 128 + wave * 32 + (lane >> 2)) * CDIM + (lane & 3) * 8;
  __hip_bfloat16* aDst = &As[(wave * 32) * 32];
  __hip_bfloat16* bDst = &Bs[(wave * 32) * 32];

  const int wr = wave >> 1, wc = wave & 1;           // 2x2 wave grid, 64x64 each
  const int ar = lane & 15, ak = (lane >> 4) * 8;    // mfma A/B operand layout
  const int aoff = (wr * 64 + ar) * 32 + ak;
  const int boff = (wc * 64 + ar) * 32 + ak;

  f32x4 acc[4][4] = {};

  for (int k0 = 0; k0 < CDIM; k0 += 32) {
    gload_lds16(aSrc + k0,              aDst);
    gload_lds16(aSrc + k0 + 16 * CDIM,  aDst + 16 * 32);
    gload_lds16(bSrc + k0,              bDst);
    gload_lds16(bSrc + k0 + 16 * CDIM,  bDst + 16 * 32);
    __syncthreads();

    short8 af[4], bfr[4];
#pragma unroll
    for (int i = 0; i < 4; ++i)
      af[i] = *(const short8*)&As[aoff + i * 16 * 32];
#pragma unroll
    for (int i = 0; i < 4; ++i)
      bfr[i] = *(const short8*)&Bs[boff + i * 16 * 32];
#pragma unroll
    for (int i = 0; i < 4; ++i)
#pragma unroll
      for (int j = 0; j < 4; ++j)
        acc[i][j] = __builtin_amdgcn_mfma_f32_16x16x32_bf16(af[i], bfr[j], acc[i][j], 0, 0, 0);
    __syncthreads();
  }

  // epilogue: BN (inference, folded) + ReLU, store bf16.
  // C/D layout: col = lane&15, row = (lane>>4)*4 + reg  [m89 verified]
#pragma unroll
  for (int jn = 0; jn < 4; ++jn) {
    const int col = nt * 128 + wc * 64 + jn * 16 + (lane & 15);
    const float sc = gp[h * CDIM + col] / sqrtf(vp[h * CDIM + col] + BN_EPS);
    const float sh = bp[h * CDIM + col] - mp[h * CDIM + col] * sc;
#pragma unroll
    for (int i = 0; i < 4; ++i) {
      const int row = mt * 128 + wr * 64 + i * 16 + (lane >> 4) * 4;
#pragma unroll
      for (int r = 0; r < 4; ++r) {
        float val = acc[i][jn][r] * sc + sh;
        val = val > 0.f ? val : 0.f;
        out[((size_t)h * MROWS + row + r) * CDIM + col] = __float2bfloat16(val);
      }
    }
  }
}

// ---------------------------------------------------------------------------
// Final 1x1 conv per head: out[m][off_h + j] = act3[h][m][:] . Wf[j][:] + bf[j]
// One wave per (h, m). act bf16, weights fp32 (L2-resident).
// ---------------------------------------------------------------------------
template <int CH>
__device__ __forceinline__ void head_dot(const __hip_bfloat16* xrow,
                                         const float* __restrict__ Wf,
                                         const float* __restrict__ bfv,
                                         float* outp, int lane) {
  float xv[32];
  const short8* xp = (const short8*)(xrow + lane * 32);
#pragma unroll
  for (int q = 0; q < 4; ++q) {
    short8 s = xp[q];
#pragma unroll
    for (int j = 0; j < 8; ++j) {
      unsigned int bits = ((unsigned int)(unsigned short)s[j]) << 16;
      xv[q * 8 + j] = __uint_as_float(bits);
    }
  }
  float acc[CH];
#pragma unroll
  for (int j = 0; j < CH; ++j) {
    const float4* wr = (const float4*)(Wf + j * 2048 + lane * 32);
    float a = 0.f;
#pragma unroll
    for (int q = 0; q < 8; ++q) {
      float4 w = wr[q];
      a += xv[q * 4 + 0] * w.x + xv[q * 4 + 1] * w.y +
           xv[q * 4 + 2] * w.z + xv[q * 4 + 3] * w.w;
    }
    acc[j] = a;
  }
#pragma unroll
  for (int j = 0; j < CH; ++j) {
    float a = acc[j];
#pragma unroll
    for (int s = 32; s > 0; s >>= 1) a += __shfl_xor(a, s, 64);
    if (lane == 0) outp[j] = a + bfv[j];
  }
}

__global__ __launch_bounds__(256) void final_heads(
    const __hip_bfloat16* __restrict__ act,
    const float* __restrict__ Wf0, const float* __restrict__ bf0,
    const float* __restrict__ Wf1, const float* __restrict__ bf1,
    const float* __restrict__ Wf2, const float* __restrict__ bf2,
    float* __restrict__ out)
{
  const int gw   = (int)((blockIdx.x * blockDim.x + threadIdx.x) >> 6);
  const int lane = threadIdx.x & 63;
  const int h    = gw >> 12;       // / 4096
  const int mrow = gw & 4095;
  const __hip_bfloat16* xrow = act + ((size_t)h * MROWS + mrow) * CDIM;
  float* outp = out + (size_t)mrow * 26;
  if (h == 0)      head_dot<16>(xrow, Wf0, bf0, outp + 0,  lane);
  else if (h == 1) head_dot<5>(xrow, Wf1, bf1, outp + 16, lane);
  else             head_dot<5>(xrow, Wf2, bf2, outp + 21, lane);
}

// ---------------------------------------------------------------------------
extern "C" void kernel_launch(void* const* d_in, const int* in_sizes, int n_in,
                              void* d_out, int out_size, void* d_ws, size_t ws_size,
                              hipStream_t stream) {
  const float* feat = (const float*)d_in[0];
  const float* W1 = (const float*)d_in[1];
  const float* g1 = (const float*)d_in[2];
  const float* b1 = (const float*)d_in[3];
  const float* m1 = (const float*)d_in[4];
  const float* v1 = (const float*)d_in[5];
  const float* W2 = (const float*)d_in[6];
  const float* g2 = (const float*)d_in[7];
  const float* b2 = (const float*)d_in[8];
  const float* m2 = (const float*)d_in[9];
  const float* v2 = (const float*)d_in[10];
  const float* W3 = (const float*)d_in[11];
  const float* g3 = (const float*)d_in[12];
  const float* b3 = (const float*)d_in[13];
  const float* m3 = (const float*)d_in[14];
  const float* v3 = (const float*)d_in[15];
  const float* Wf0 = (const float*)d_in[16];
  const float* bf0 = (const float*)d_in[17];
  const float* Wf1 = (const float*)d_in[18];
  const float* bf1 = (const float*)d_in[19];
  const float* Wf2 = (const float*)d_in[20];
  const float* bf2 = (const float*)d_in[21];
  float* out = (float*)d_out;

  // workspace layout (bytes):
  //   wbuf : 3*2048*2048*2      = 25,165,824   (current layer's bf16 weights)
  //   actA : 3*4096*2048*2      = 50,331,648
  //   actB : 3*4096*2048*2      = 50,331,648   (xb overlaps actB's start)
  char* ws = (char*)d_ws;
  __hip_bfloat16* wbuf = (__hip_bfloat16*)ws;
  __hip_bfloat16* actA = (__hip_bfloat16*)(ws + 25165824);
  __hip_bfloat16* actB = (__hip_bfloat16*)(ws + 25165824 + 50331648);
  __hip_bfloat16* xb   = actB;  // features bf16; dead once layer2 writes actB

  const int nW4 = (3 * CDIM * CDIM) / 4;   // 3,145,728
  const int nX4 = (MROWS * CDIM) / 4;      // 2,097,152
  const long long hstride = (long long)MROWS * CDIM;

  cvt_f32_bf16<<<2048, 256, 0, stream>>>(feat, (unsigned short*)xb, nX4);

  cvt_f32_bf16<<<2048, 256, 0, stream>>>(W1, (unsigned short*)wbuf, nW4);
  gemm_bn_relu<<<dim3(512, 3), 256, 0, stream>>>(xb, 0LL, wbuf, g1, b1, m1, v1, actA);

  cvt_f32_bf16<<<2048, 256, 0, stream>>>(W2, (unsigned short*)wbuf, nW4);
  gemm_bn_relu<<<dim3(512, 3), 256, 0, stream>>>(actA, hstride, wbuf, g2, b2, m2, v2, actB);

  cvt_f32_bf16<<<2048, 256, 0, stream>>>(W3, (unsigned short*)wbuf, nW4);
  gemm_bn_relu<<<dim3(512, 3), 256, 0, stream>>>(actB, hstride, wbuf, g3, b3, m3, v3, actA);

  final_heads<<<3072, 256, 0, stream>>>(actA, Wf0, bf0, Wf1, bf1, Wf2, bf2, out);
}

// Round 2
// 512.757 us; speedup vs baseline: 1.0297x; 1.0297x over previous
//
#include <hip/hip_runtime.h>
#include <hip/hip_bf16.h>

typedef __attribute__((ext_vector_type(8))) short short8;
typedef __attribute__((ext_vector_type(4))) float f32x4;

#define BN_EPS 1e-5f
#define MROWS 4096
#define CDIM 2048
#define NKT 32   // K tiles of 64

__device__ __forceinline__ void gload_lds16(const void* g, void* l) {
  __builtin_amdgcn_global_load_lds(
      (const __attribute__((address_space(1))) void*)g,
      (__attribute__((address_space(3))) void*)l, 16, 0, 0);
}

// ---------------------------------------------------------------------------
// fp32 -> bf16 conversion (vectorized float4 -> ushort4)
// ---------------------------------------------------------------------------
__global__ __launch_bounds__(256) void cvt_f32_bf16(const float* __restrict__ in,
                                                    unsigned short* __restrict__ out,
                                                    int n4) {
  int idx = blockIdx.x * blockDim.x + threadIdx.x;
  int stride = gridDim.x * blockDim.x;
  for (int i = idx; i < n4; i += stride) {
    float4 vv = ((const float4*)in)[i];
    __hip_bfloat16 h0 = __float2bfloat16(vv.x);
    __hip_bfloat16 h1 = __float2bfloat16(vv.y);
    __hip_bfloat16 h2 = __float2bfloat16(vv.z);
    __hip_bfloat16 h3 = __float2bfloat16(vv.w);
    ushort4 o;
    o.x = *(unsigned short*)&h0;
    o.y = *(unsigned short*)&h1;
    o.z = *(unsigned short*)&h2;
    o.w = *(unsigned short*)&h3;
    ((ushort4*)out)[i] = o;
  }
}

// ---------------------------------------------------------------------------
// 256x256-tile, BK=64, 8-phase counted-vmcnt GEMM (m201 template port).
// out[h][m][d] = relu( (sum_c A[h][m][c]*W[h][d][c]) * scale + shift )
// 512 threads = 8 waves (2M x 4N), per-wave 128x64, acc[8][4].
// LDS 128KiB: [dbuf2][mat2][half2][128x64] bf16, st-swizzle chunk^=(row&7)
// applied via inverse-permuted global source + swizzled ds_read address.
// ---------------------------------------------------------------------------
__global__ __launch_bounds__(512, 2) void gemm256_bn_relu(
    const __hip_bfloat16* __restrict__ A, long long a_hstride,
    const __hip_bfloat16* __restrict__ W,
    const float* __restrict__ gp, const float* __restrict__ bp,
    const float* __restrict__ mp, const float* __restrict__ vp,
    __hip_bfloat16* __restrict__ out)
{
  __shared__ __hip_bfloat16 sm[65536];   // 128 KiB

  const int tid  = threadIdx.x;
  const int w    = tid >> 6;
  const int lane = tid & 63;

  // XCD-bijective swizzle over 384 blocks (384 % 8 == 0)
  const int bid = blockIdx.x;
  const int swz = (bid & 7) * 48 + (bid >> 3);
  const int h   = swz >> 7;          // 128 blocks per head
  const int mt  = (swz & 127) >> 3;  // 16 m-tiles
  const int nt  = swz & 7;           // 8 n-tiles

  const __hip_bfloat16* Abase = A + (size_t)h * (size_t)a_hstride + (size_t)(mt * 256) * CDIM;
  const __hip_bfloat16* Bbase = W + ((size_t)h * CDIM + (size_t)(nt * 256)) * CDIM;

  // staging addressing: half-tile = 128 rows x 64 cols bf16 = 1024 x 16B slots.
  // wave w writes slots [w*128, w*128+128) via 2 insts; slot s -> row=s>>3,
  // lds chunk c=s&7 holds global chunk c^(row&7) (inverse of read swizzle).
  const int slot0 = w * 128 + lane;
  const int srow  = slot0 >> 3;
  const int gcol  = ((slot0 & 7) ^ (srow & 7)) << 3;  // element offset

  // fragment read offsets (swizzled): chunk g at row r lives at chunk g^(r&7)
  const int wm = w >> 2;             // 0..1  -> A half
  const int wn = w & 3;              // 0..3  -> B half = wn>>1, col = (wn&1)*64
  const int fr = lane & 15;
  const int fg = lane >> 4;
  const int offs0 = fr * 64 + ((fg ^ (fr & 7)) << 3);        // ksub 0
  const int offs1 = fr * 64 + (((fg + 4) ^ (fr & 7)) << 3);  // ksub 1
  const int aOff = wm * 8192;
  const int bOff = 16384 + (wn >> 1) * 8192 + (wn & 1) * 4096;

  auto STAGE = [&](int dbuf, int mat, int ih, int t) {
    const __hip_bfloat16* sp = (mat ? Bbase : Abase)
        + (size_t)(ih * 128 + srow) * CDIM + t * 64 + gcol;
    __hip_bfloat16* dp = &sm[dbuf * 32768 + mat * 16384 + ih * 8192 + w * 1024];
    gload_lds16(sp, dp);
    gload_lds16(sp + 8 * CDIM, dp + 512);
  };

  f32x4 acc[8][4] = {};
  short8 a8[4][2], b8[4][2];

  // prologue: tile0 fully + half0(A0) of tile1; allow tile1's half in flight.
  STAGE(0, 0, 0, 0); STAGE(0, 0, 1, 0); STAGE(0, 1, 0, 0); STAGE(0, 1, 1, 0);
  STAGE(1, 0, 0, 1);
  asm volatile("s_waitcnt vmcnt(2)" ::: "memory");
  __builtin_amdgcn_sched_barrier(0);
  __builtin_amdgcn_s_barrier();
  __builtin_amdgcn_sched_barrier(0);

#pragma unroll 2
  for (int t = 0; t < NKT; ++t) {
    const int d = t & 1, dn = d ^ 1;
    const __hip_bfloat16* aH = &sm[d * 32768 + aOff];
    const __hip_bfloat16* bH = &sm[d * 32768 + bOff];

    // ---- phase 0: read A(i0-3), B(j0-1); stage A1(t+1); mfma i0-3 x j0-1 ----
#pragma unroll
    for (int i = 0; i < 4; ++i) {
      a8[i][0] = *(const short8*)(aH + i * 1024 + offs0);
      a8[i][1] = *(const short8*)(aH + i * 1024 + offs1);
    }
#pragma unroll
    for (int j = 0; j < 2; ++j) {
      b8[j][0] = *(const short8*)(bH + j * 1024 + offs0);
      b8[j][1] = *(const short8*)(bH + j * 1024 + offs1);
    }
    if (t + 1 < NKT) STAGE(dn, 0, 1, t + 1);
    __builtin_amdgcn_sched_barrier(0);
    __builtin_amdgcn_s_barrier();
    asm volatile("s_waitcnt lgkmcnt(0)" ::: "memory");
    __builtin_amdgcn_sched_barrier(0);
    __builtin_amdgcn_s_setprio(1);
#pragma unroll
    for (int i = 0; i < 4; ++i)
#pragma unroll
      for (int j = 0; j < 2; ++j) {
        acc[i][j] = __builtin_amdgcn_mfma_f32_16x16x32_bf16(a8[i][0], b8[j][0], acc[i][j], 0, 0, 0);
        acc[i][j] = __builtin_amdgcn_mfma_f32_16x16x32_bf16(a8[i][1], b8[j][1], acc[i][j], 0, 0, 0);
      }
    __builtin_amdgcn_s_setprio(0);
    __builtin_amdgcn_sched_barrier(0);
    __builtin_amdgcn_s_barrier();
    __builtin_amdgcn_sched_barrier(0);

    // ---- phase 1: read B(j2-3); stage B0(t+1); mfma i0-3 x j2-3 ----
#pragma unroll
    for (int j = 2; j < 4; ++j) {
      b8[j][0] = *(const short8*)(bH + j * 1024 + offs0);
      b8[j][1] = *(const short8*)(bH + j * 1024 + offs1);
    }
    if (t + 1 < NKT) STAGE(dn, 1, 0, t + 1);
    __builtin_amdgcn_sched_barrier(0);
    __builtin_amdgcn_s_barrier();
    asm volatile("s_waitcnt lgkmcnt(0)" ::: "memory");
    __builtin_amdgcn_sched_barrier(0);
    __builtin_amdgcn_s_setprio(1);
#pragma unroll
    for (int i = 0; i < 4; ++i)
#pragma unroll
      for (int j = 2; j < 4; ++j) {
        acc[i][j] = __builtin_amdgcn_mfma_f32_16x16x32_bf16(a8[i][0], b8[j][0], acc[i][j], 0, 0, 0);
        acc[i][j] = __builtin_amdgcn_mfma_f32_16x16x32_bf16(a8[i][1], b8[j][1], acc[i][j], 0, 0, 0);
      }
    __builtin_amdgcn_s_setprio(0);
    __builtin_amdgcn_sched_barrier(0);
    __builtin_amdgcn_s_barrier();
    __builtin_amdgcn_sched_barrier(0);

    // ---- phase 2: read A(i4-7); stage B1(t+1); mfma i4-7 x j2-3 ----
#pragma unroll
    for (int i = 0; i < 4; ++i) {
      a8[i][0] = *(const short8*)(aH + (i + 4) * 1024 + offs0);
      a8[i][1] = *(const short8*)(aH + (i + 4) * 1024 + offs1);
    }
    if (t + 1 < NKT) STAGE(dn, 1, 1, t + 1);
    __builtin_amdgcn_sched_barrier(0);
    __builtin_amdgcn_s_barrier();
    asm volatile("s_waitcnt lgkmcnt(0)" ::: "memory");
    __builtin_amdgcn_sched_barrier(0);
    __builtin_amdgcn_s_setprio(1);
#pragma unroll
    for (int i = 0; i < 4; ++i)
#pragma unroll
      for (int j = 2; j < 4; ++j) {
        acc[i + 4][j] = __builtin_amdgcn_mfma_f32_16x16x32_bf16(a8[i][0], b8[j][0], acc[i + 4][j], 0, 0, 0);
        acc[i + 4][j] = __builtin_amdgcn_mfma_f32_16x16x32_bf16(a8[i][1], b8[j][1], acc[i + 4][j], 0, 0, 0);
      }
    __builtin_amdgcn_s_setprio(0);
    __builtin_amdgcn_sched_barrier(0);
    __builtin_amdgcn_s_barrier();
    __builtin_amdgcn_sched_barrier(0);

    // ---- phase 3: stage A0(t+2); mfma i4-7 x j0-1; vmcnt checkpoint ----
    if (t + 2 < NKT) STAGE(d, 0, 0, t + 2);
    __builtin_amdgcn_sched_barrier(0);
    __builtin_amdgcn_s_barrier();
    __builtin_amdgcn_sched_barrier(0);
    __builtin_amdgcn_s_setprio(1);
#pragma unroll
    for (int i = 0; i < 4; ++i)
#pragma unroll
      for (int j = 0; j < 2; ++j) {
        acc[i + 4][j] = __builtin_amdgcn_mfma_f32_16x16x32_bf16(a8[i][0], b8[j][0], acc[i + 4][j], 0, 0, 0);
        acc[i + 4][j] = __builtin_amdgcn_mfma_f32_16x16x32_bf16(a8[i][1], b8[j][1], acc[i + 4][j], 0, 0, 0);
      }
    __builtin_amdgcn_s_setprio(0);
    __builtin_amdgcn_sched_barrier(0);
    if (t + 2 < NKT) { asm volatile("s_waitcnt vmcnt(2)" ::: "memory"); }
    else             { asm volatile("s_waitcnt vmcnt(0)" ::: "memory"); }
    __builtin_amdgcn_sched_barrier(0);
    __builtin_amdgcn_s_barrier();
    __builtin_amdgcn_sched_barrier(0);
  }

  // epilogue: BN (folded) + ReLU, bf16 store.
  // C/D layout: col = lane&15, row = (lane>>4)*4 + reg  [m89 verified]
  const float* gh = gp + h * CDIM;
  const float* bh = bp + h * CDIM;
  const float* mh = mp + h * CDIM;
  const float* vh = vp + h * CDIM;
  const int colBase = nt * 256 + wn * 64 + fr;
  const int rowBase = mt * 256 + wm * 128 + fg * 4;
#pragma unroll
  for (int j = 0; j < 4; ++j) {
    const int col = colBase + j * 16;
    const float sc = gh[col] / sqrtf(vh[col] + BN_EPS);
    const float sh = bh[col] - mh[col] * sc;
#pragma unroll
    for (int i = 0; i < 8; ++i) {
      const int row = rowBase + i * 16;
#pragma unroll
      for (int rr = 0; rr < 4; ++rr) {
        float val = acc[i][j][rr] * sc + sh;
        val = val > 0.f ? val : 0.f;
        out[((size_t)h * MROWS + row + rr) * CDIM + col] = __float2bfloat16(val);
      }
    }
  }
}

// ---------------------------------------------------------------------------
// Final 1x1 conv per head: out[m][off_h + j] = act3[h][m][:] . Wf[j][:] + bf[j]
// ---------------------------------------------------------------------------
template <int CH>
__device__ __forceinline__ void head_dot(const __hip_bfloat16* xrow,
                                         const float* __restrict__ Wf,
                                         const float* __restrict__ bfv,
                                         float* outp, int lane) {
  float xv[32];
  const short8* xp = (const short8*)(xrow + lane * 32);
#pragma unroll
  for (int q = 0; q < 4; ++q) {
    short8 s = xp[q];
#pragma unroll
    for (int j = 0; j < 8; ++j) {
      unsigned int bits = ((unsigned int)(unsigned short)s[j]) << 16;
      xv[q * 8 + j] = __uint_as_float(bits);
    }
  }
  float acc[CH];
#pragma unroll
  for (int j = 0; j < CH; ++j) {
    const float4* wr = (const float4*)(Wf + j * 2048 + lane * 32);
    float a = 0.f;
#pragma unroll
    for (int q = 0; q < 8; ++q) {
      float4 w = wr[q];
      a += xv[q * 4 + 0] * w.x + xv[q * 4 + 1] * w.y +
           xv[q * 4 + 2] * w.z + xv[q * 4 + 3] * w.w;
    }
    acc[j] = a;
  }
#pragma unroll
  for (int j = 0; j < CH; ++j) {
    float a = acc[j];
#pragma unroll
    for (int s = 32; s > 0; s >>= 1) a += __shfl_xor(a, s, 64);
    if (lane == 0) outp[j] = a + bfv[j];
  }
}

__global__ __launch_bounds__(256) void final_heads(
    const __hip_bfloat16* __restrict__ act,
    const float* __restrict__ Wf0, const float* __restrict__ bf0,
    const float* __restrict__ Wf1, const float* __restrict__ bf1,
    const float* __restrict__ Wf2, const float* __restrict__ bf2,
    float* __restrict__ out)
{
  const int gw   = (int)((blockIdx.x * blockDim.x + threadIdx.x) >> 6);
  const int lane = threadIdx.x & 63;
  const int h    = gw >> 12;
  const int mrow = gw & 4095;
  const __hip_bfloat16* xrow = act + ((size_t)h * MROWS + mrow) * CDIM;
  float* outp = out + (size_t)mrow * 26;
  if (h == 0)      head_dot<16>(xrow, Wf0, bf0, outp + 0,  lane);
  else if (h == 1) head_dot<5>(xrow, Wf1, bf1, outp + 16, lane);
  else             head_dot<5>(xrow, Wf2, bf2, outp + 21, lane);
}

// ---------------------------------------------------------------------------
extern "C" void kernel_launch(void* const* d_in, const int* in_sizes, int n_in,
                              void* d_out, int out_size, void* d_ws, size_t ws_size,
                              hipStream_t stream) {
  const float* feat = (const float*)d_in[0];
  const float* W1 = (const float*)d_in[1];
  const float* g1 = (const float*)d_in[2];
  const float* b1 = (const float*)d_in[3];
  const float* m1 = (const float*)d_in[4];
  const float* v1 = (const float*)d_in[5];
  const float* W2 = (const float*)d_in[6];
  const float* g2 = (const float*)d_in[7];
  const float* b2 = (const float*)d_in[8];
  const float* m2 = (const float*)d_in[9];
  const float* v2 = (const float*)d_in[10];
  const float* W3 = (const float*)d_in[11];
  const float* g3 = (const float*)d_in[12];
  const float* b3 = (const float*)d_in[13];
  const float* m3 = (const float*)d_in[14];
  const float* v3 = (const float*)d_in[15];
  const float* Wf0 = (const float*)d_in[16];
  const float* bf0 = (const float*)d_in[17];
  const float* Wf1 = (const float*)d_in[18];
  const float* bf1 = (const float*)d_in[19];
  const float* Wf2 = (const float*)d_in[20];
  const float* bf2 = (const float*)d_in[21];
  float* out = (float*)d_out;

  // workspace: wbuf 24MB | actA 48MB | actB 48MB (features bf16 overlaps actB)
  char* ws = (char*)d_ws;
  __hip_bfloat16* wbuf = (__hip_bfloat16*)ws;
  __hip_bfloat16* actA = (__hip_bfloat16*)(ws + 25165824);
  __hip_bfloat16* actB = (__hip_bfloat16*)(ws + 25165824 + 50331648);
  __hip_bfloat16* xb   = actB;

  const int nW4 = (3 * CDIM * CDIM) / 4;
  const int nX4 = (MROWS * CDIM) / 4;
  const long long hstride = (long long)MROWS * CDIM;

  cvt_f32_bf16<<<2048, 256, 0, stream>>>(feat, (unsigned short*)xb, nX4);

  cvt_f32_bf16<<<2048, 256, 0, stream>>>(W1, (unsigned short*)wbuf, nW4);
  gemm256_bn_relu<<<384, 512, 0, stream>>>(xb, 0LL, wbuf, g1, b1, m1, v1, actA);

  cvt_f32_bf16<<<2048, 256, 0, stream>>>(W2, (unsigned short*)wbuf, nW4);
  gemm256_bn_relu<<<384, 512, 0, stream>>>(actA, hstride, wbuf, g2, b2, m2, v2, actB);

  cvt_f32_bf16<<<2048, 256, 0, stream>>>(W3, (unsigned short*)wbuf, nW4);
  gemm256_bn_relu<<<384, 512, 0, stream>>>(actB, hstride, wbuf, g3, b3, m3, v3, actA);

  final_heads<<<3072, 256, 0, stream>>>(actA, Wf0, bf0, Wf1, bf1, Wf2, bf2, out);
}

// Round 3
// 461.668 us; speedup vs baseline: 1.1437x; 1.1107x over previous
//
#include <hip/hip_runtime.h>
#include <hip/hip_bf16.h>

typedef __attribute__((ext_vector_type(8))) short short8;
typedef __attribute__((ext_vector_type(4))) float f32x4;

#define BN_EPS 1e-5f
#define MROWS 4096
#define CDIM 2048
#define NKT 32   // K tiles of 64

#define SB() __builtin_amdgcn_sched_barrier(0)

__device__ __forceinline__ void gload_lds16(const void* g, void* l) {
  __builtin_amdgcn_global_load_lds(
      (const __attribute__((address_space(1))) void*)g,
      (__attribute__((address_space(3))) void*)l, 16, 0, 0);
}

// ---------------------------------------------------------------------------
// fp32 -> bf16 conversion (vectorized float4 -> ushort4)
// ---------------------------------------------------------------------------
__global__ __launch_bounds__(256) void cvt_f32_bf16(const float* __restrict__ in,
                                                    unsigned short* __restrict__ out,
                                                    int n4) {
  int idx = blockIdx.x * blockDim.x + threadIdx.x;
  int stride = gridDim.x * blockDim.x;
  for (int i = idx; i < n4; i += stride) {
    float4 vv = ((const float4*)in)[i];
    __hip_bfloat16 h0 = __float2bfloat16(vv.x);
    __hip_bfloat16 h1 = __float2bfloat16(vv.y);
    __hip_bfloat16 h2 = __float2bfloat16(vv.z);
    __hip_bfloat16 h3 = __float2bfloat16(vv.w);
    ushort4 o;
    o.x = *(unsigned short*)&h0;
    o.y = *(unsigned short*)&h1;
    o.z = *(unsigned short*)&h2;
    o.w = *(unsigned short*)&h3;
    ((ushort4*)out)[i] = o;
  }
}

// ---------------------------------------------------------------------------
// 256x256 tile, BK=64, fragment-pipelined GEMM (reads run UNDER MFMA).
// 8 waves (2M x 4N), per-wave 128x64, acc[8][4]; 2 barriers per K-tile.
// K-tile = 8 groups of 8 MFMA (quadrant x ksub); each group's trailing
// ds_reads refill the fragment set that just died, >=2 groups before use.
// LDS 128KiB [dbuf2][A/B][half2][128x64] bf16, XOR-swizzled (R2-verified).
// ---------------------------------------------------------------------------
__global__ __launch_bounds__(512, 2) void gemm256_bn_relu(
    const __hip_bfloat16* __restrict__ A, long long a_hstride,
    const __hip_bfloat16* __restrict__ W,
    const float* __restrict__ gp, const float* __restrict__ bp,
    const float* __restrict__ mp, const float* __restrict__ vp,
    __hip_bfloat16* __restrict__ out)
{
  __shared__ __hip_bfloat16 sm[65536];   // 128 KiB

  const int tid  = threadIdx.x;
  const int w    = tid >> 6;
  const int lane = tid & 63;

  // XCD-bijective swizzle over 384 blocks (384 % 8 == 0)
  const int bid = blockIdx.x;
  const int swz = (bid & 7) * 48 + (bid >> 3);
  const int h   = swz >> 7;
  const int mt  = (swz & 127) >> 3;
  const int nt  = swz & 7;

  const __hip_bfloat16* Abase = A + (size_t)h * (size_t)a_hstride + (size_t)(mt * 256) * CDIM;
  const __hip_bfloat16* Bbase = W + ((size_t)h * CDIM + (size_t)(nt * 256)) * CDIM;

  // staging: half-tile = 128x64 bf16 = 1024 16B slots; wave w owns 128 slots.
  const int slot0 = w * 128 + lane;
  const int srow  = slot0 >> 3;
  const int gcol  = ((slot0 & 7) ^ (srow & 7)) << 3;

  const int wm = w >> 2;
  const int wn = w & 3;
  const int fr = lane & 15;
  const int fg = lane >> 4;
  const int offs0 = fr * 64 + ((fg ^ (fr & 7)) << 3);        // ksub 0
  const int offs1 = fr * 64 + (((fg + 4) ^ (fr & 7)) << 3);  // ksub 1
  const int aOff = wm * 8192;
  const int bOff = 16384 + (wn >> 1) * 8192 + (wn & 1) * 4096;

  auto STAGE = [&](int dbuf, int mat, int ih, int t) {
    const __hip_bfloat16* sp = (mat ? Bbase : Abase)
        + (size_t)(ih * 128 + srow) * CDIM + t * 64 + gcol;
    __hip_bfloat16* dp = &sm[dbuf * 32768 + mat * 16384 + ih * 8192 + w * 1024];
    gload_lds16(sp, dp);
    gload_lds16(sp + 8 * CDIM, dp + 512);
  };

  f32x4 acc[8][4] = {};
  short8 A0[4], A1[4], B0[2], B1[2];

  const __hip_bfloat16* aB[2] = { &sm[aOff], &sm[32768 + aOff] };
  const __hip_bfloat16* bB[2] = { &sm[bOff], &sm[32768 + bOff] };

#define LDA(dst, base, i0, offs)                                        \
  _Pragma("unroll") for (int i_ = 0; i_ < 4; ++i_)                      \
    dst[i_] = *(const short8*)((base) + ((i0) + i_) * 1024 + (offs));
#define LDB(dst, base, j0, offs)                                        \
  _Pragma("unroll") for (int j_ = 0; j_ < 2; ++j_)                      \
    dst[j_] = *(const short8*)((base) + ((j0) + j_) * 1024 + (offs));

#define MFMA_Q(ioff, joff, Aset, Bset)                                  \
  __builtin_amdgcn_s_setprio(1);                                        \
  _Pragma("unroll") for (int i_ = 0; i_ < 4; ++i_)                      \
  _Pragma("unroll") for (int j_ = 0; j_ < 2; ++j_)                      \
    acc[i_ + ioff][j_ + joff] = __builtin_amdgcn_mfma_f32_16x16x32_bf16( \
        Aset[i_], Bset[j_], acc[i_ + ioff][j_ + joff], 0, 0, 0);        \
  __builtin_amdgcn_s_setprio(0);

  // ---- prologue: stage tile0 (4 halves) + Ah0(1); pre-read s0 fragments ----
  STAGE(0, 0, 0, 0); STAGE(0, 0, 1, 0); STAGE(0, 1, 0, 0); STAGE(0, 1, 1, 0);
  STAGE(1, 0, 0, 1);
  asm volatile("s_waitcnt vmcnt(2)" ::: "memory");
  SB();
  __builtin_amdgcn_s_barrier();
  SB();
  LDA(A0, aB[0], 0, offs0);
  LDA(A1, aB[0], 4, offs0);
  LDB(B0, bB[0], 0, offs0);
  LDB(B1, bB[0], 2, offs0);
  SB();

#pragma unroll 2
  for (int t = 0; t < NKT - 1; ++t) {
    const int d = t & 1, dn = d ^ 1;
    const __hip_bfloat16* aHd = aB[d];
    const __hip_bfloat16* bHd = bB[d];
    const __hip_bfloat16* aHn = aB[dn];
    const __hip_bfloat16* bHn = bB[dn];

    // g0: Q0 s0
    MFMA_Q(0, 0, A0, B0); SB();
    STAGE(dn, 0, 1, t + 1); SB();
    // g1: Q1 s0; refill A0 <- s1(t)
    MFMA_Q(0, 2, A0, B1); SB();
    LDA(A0, aHd, 0, offs1); SB();
    // g2: Q3 s0; refill B0 <- s1(t)
    MFMA_Q(4, 0, A1, B0); SB();
    STAGE(dn, 1, 0, t + 1);
    LDB(B0, bHd, 0, offs1); SB();
    // g3: Q2 s0; refill B1,A1 <- s1(t)
    MFMA_Q(4, 2, A1, B1); SB();
    STAGE(dn, 1, 1, t + 1);
    LDB(B1, bHd, 2, offs1);
    LDA(A1, aHd, 4, offs1); SB();
    // g4: Q0 s1
    MFMA_Q(0, 0, A0, B0); SB();
    if (t + 2 < NKT) { STAGE(d, 0, 0, t + 2); }
    SB();
    // g5: Q1 s1; sync S1 (A halves of t+1 landed); refill A0 <- s0(t+1)
    MFMA_Q(0, 2, A0, B1); SB();
    if (t + 2 < NKT) { asm volatile("s_waitcnt vmcnt(6)" ::: "memory"); }
    else             { asm volatile("s_waitcnt vmcnt(4)" ::: "memory"); }
    SB();
    __builtin_amdgcn_s_barrier();
    SB();
    LDA(A0, aHn, 0, offs0); SB();
    // g6: Q3 s1; sync S2 (B of t+1 landed); refill B0 <- s0(t+1)
    MFMA_Q(4, 0, A1, B0); SB();
    if (t + 2 < NKT) { asm volatile("s_waitcnt vmcnt(2)" ::: "memory"); }
    else             { asm volatile("s_waitcnt vmcnt(0)" ::: "memory"); }
    SB();
    __builtin_amdgcn_s_barrier();
    SB();
    LDB(B0, bHn, 0, offs0); SB();
    // g7: Q2 s1; refill B1,A1 <- s0(t+1)
    MFMA_Q(4, 2, A1, B1); SB();
    LDB(B1, bHn, 2, offs0);
    LDA(A1, aHn, 4, offs0); SB();
  }

  // ---- peeled last tile (t = NKT-1, dbuf = (NKT-1)&1) ----
  {
    const int d = (NKT - 1) & 1;
    const __hip_bfloat16* aHd = aB[d];
    const __hip_bfloat16* bHd = bB[d];
    MFMA_Q(0, 0, A0, B0); SB();
    MFMA_Q(0, 2, A0, B1); SB();
    LDA(A0, aHd, 0, offs1); SB();
    MFMA_Q(4, 0, A1, B0); SB();
    LDB(B0, bHd, 0, offs1); SB();
    MFMA_Q(4, 2, A1, B1); SB();
    LDB(B1, bHd, 2, offs1);
    LDA(A1, aHd, 4, offs1); SB();
    MFMA_Q(0, 0, A0, B0); SB();
    MFMA_Q(0, 2, A0, B1); SB();
    MFMA_Q(4, 0, A1, B0); SB();
    MFMA_Q(4, 2, A1, B1); SB();
  }

  // epilogue: BN (folded) + ReLU, bf16 store.
  // C/D layout: col = lane&15, row = (lane>>4)*4 + reg  [m89 verified]
  const float* gh = gp + h * CDIM;
  const float* bh = bp + h * CDIM;
  const float* mh = mp + h * CDIM;
  const float* vh = vp + h * CDIM;
  const int colBase = nt * 256 + wn * 64 + fr;
  const int rowBase = mt * 256 + wm * 128 + fg * 4;
#pragma unroll
  for (int j = 0; j < 4; ++j) {
    const int col = colBase + j * 16;
    const float sc = gh[col] / sqrtf(vh[col] + BN_EPS);
    const float sh = bh[col] - mh[col] * sc;
#pragma unroll
    for (int i = 0; i < 8; ++i) {
      const int row = rowBase + i * 16;
#pragma unroll
      for (int rr = 0; rr < 4; ++rr) {
        float val = acc[i][j][rr] * sc + sh;
        val = val > 0.f ? val : 0.f;
        out[((size_t)h * MROWS + row + rr) * CDIM + col] = __float2bfloat16(val);
      }
    }
  }
}

// ---------------------------------------------------------------------------
// Final 1x1 conv per head: out[m][off_h + j] = act3[h][m][:] . Wf[j][:] + bf[j]
// ---------------------------------------------------------------------------
template <int CH>
__device__ __forceinline__ void head_dot(const __hip_bfloat16* xrow,
                                         const float* __restrict__ Wf,
                                         const float* __restrict__ bfv,
                                         float* outp, int lane) {
  float xv[32];
  const short8* xp = (const short8*)(xrow + lane * 32);
#pragma unroll
  for (int q = 0; q < 4; ++q) {
    short8 s = xp[q];
#pragma unroll
    for (int j = 0; j < 8; ++j) {
      unsigned int bits = ((unsigned int)(unsigned short)s[j]) << 16;
      xv[q * 8 + j] = __uint_as_float(bits);
    }
  }
  float acc[CH];
#pragma unroll
  for (int j = 0; j < CH; ++j) {
    const float4* wr = (const float4*)(Wf + j * 2048 + lane * 32);
    float a = 0.f;
#pragma unroll
    for (int q = 0; q < 8; ++q) {
      float4 w = wr[q];
      a += xv[q * 4 + 0] * w.x + xv[q * 4 + 1] * w.y +
           xv[q * 4 + 2] * w.z + xv[q * 4 + 3] * w.w;
    }
    acc[j] = a;
  }
#pragma unroll
  for (int j = 0; j < CH; ++j) {
    float a = acc[j];
#pragma unroll
    for (int s = 32; s > 0; s >>= 1) a += __shfl_xor(a, s, 64);
    if (lane == 0) outp[j] = a + bfv[j];
  }
}

__global__ __launch_bounds__(256) void final_heads(
    const __hip_bfloat16* __restrict__ act,
    const float* __restrict__ Wf0, const float* __restrict__ bf0,
    const float* __restrict__ Wf1, const float* __restrict__ bf1,
    const float* __restrict__ Wf2, const float* __restrict__ bf2,
    float* __restrict__ out)
{
  const int gw   = (int)((blockIdx.x * blockDim.x + threadIdx.x) >> 6);
  const int lane = threadIdx.x & 63;
  const int h    = gw >> 12;
  const int mrow = gw & 4095;
  const __hip_bfloat16* xrow = act + ((size_t)h * MROWS + mrow) * CDIM;
  float* outp = out + (size_t)mrow * 26;
  if (h == 0)      head_dot<16>(xrow, Wf0, bf0, outp + 0,  lane);
  else if (h == 1) head_dot<5>(xrow, Wf1, bf1, outp + 16, lane);
  else             head_dot<5>(xrow, Wf2, bf2, outp + 21, lane);
}

// ---------------------------------------------------------------------------
extern "C" void kernel_launch(void* const* d_in, const int* in_sizes, int n_in,
                              void* d_out, int out_size, void* d_ws, size_t ws_size,
                              hipStream_t stream) {
  const float* feat = (const float*)d_in[0];
  const float* W1 = (const float*)d_in[1];
  const float* g1 = (const float*)d_in[2];
  const float* b1 = (const float*)d_in[3];
  const float* m1 = (const float*)d_in[4];
  const float* v1 = (const float*)d_in[5];
  const float* W2 = (const float*)d_in[6];
  const float* g2 = (const float*)d_in[7];
  const float* b2 = (const float*)d_in[8];
  const float* m2 = (const float*)d_in[9];
  const float* v2 = (const float*)d_in[10];
  const float* W3 = (const float*)d_in[11];
  const float* g3 = (const float*)d_in[12];
  const float* b3 = (const float*)d_in[13];
  const float* m3 = (const float*)d_in[14];
  const float* v3 = (const float*)d_in[15];
  const float* Wf0 = (const float*)d_in[16];
  const float* bf0 = (const float*)d_in[17];
  const float* Wf1 = (const float*)d_in[18];
  const float* bf1 = (const float*)d_in[19];
  const float* Wf2 = (const float*)d_in[20];
  const float* bf2 = (const float*)d_in[21];
  float* out = (float*)d_out;

  // workspace: wbuf 24MB | actA 48MB | actB 48MB (features bf16 overlaps actB)
  char* ws = (char*)d_ws;
  __hip_bfloat16* wbuf = (__hip_bfloat16*)ws;
  __hip_bfloat16* actA = (__hip_bfloat16*)(ws + 25165824);
  __hip_bfloat16* actB = (__hip_bfloat16*)(ws + 25165824 + 50331648);
  __hip_bfloat16* xb   = actB;

  const int nW4 = (3 * CDIM * CDIM) / 4;
  const int nX4 = (MROWS * CDIM) / 4;
  const long long hstride = (long long)MROWS * CDIM;

  cvt_f32_bf16<<<2048, 256, 0, stream>>>(feat, (unsigned short*)xb, nX4);

  cvt_f32_bf16<<<2048, 256, 0, stream>>>(W1, (unsigned short*)wbuf, nW4);
  gemm256_bn_relu<<<384, 512, 0, stream>>>(xb, 0LL, wbuf, g1, b1, m1, v1, actA);

  cvt_f32_bf16<<<2048, 256, 0, stream>>>(W2, (unsigned short*)wbuf, nW4);
  gemm256_bn_relu<<<384, 512, 0, stream>>>(actA, hstride, wbuf, g2, b2, m2, v2, actB);

  cvt_f32_bf16<<<2048, 256, 0, stream>>>(W3, (unsigned short*)wbuf, nW4);
  gemm256_bn_relu<<<384, 512, 0, stream>>>(actB, hstride, wbuf, g3, b3, m3, v3, actA);

  final_heads<<<3072, 256, 0, stream>>>(actA, Wf0, bf0, Wf1, bf1, Wf2, bf2, out);
}

// Round 4
// 361.142 us; speedup vs baseline: 1.4620x; 1.2784x over previous
//
#include <hip/hip_runtime.h>
#include <hip/hip_bf16.h>

typedef __attribute__((ext_vector_type(8))) short short8;
typedef __attribute__((ext_vector_type(4))) float f32x4;

#define BN_EPS 1e-5f
#define MROWS 4096
#define CDIM 2048
#define NKT 32   // K tiles of 64

#define SB() __builtin_amdgcn_sched_barrier(0)

__device__ __forceinline__ void gload_lds16(const void* g, void* l) {
  __builtin_amdgcn_global_load_lds(
      (const __attribute__((address_space(1))) void*)g,
      (__attribute__((address_space(3))) void*)l, 16, 0, 0);
}

// ---------------------------------------------------------------------------
// fp32 -> bf16 conversion (vectorized float4 -> ushort4)
// ---------------------------------------------------------------------------
__global__ __launch_bounds__(256) void cvt_f32_bf16(const float* __restrict__ in,
                                                    unsigned short* __restrict__ out,
                                                    int n4) {
  int idx = blockIdx.x * blockDim.x + threadIdx.x;
  int stride = gridDim.x * blockDim.x;
  for (int i = idx; i < n4; i += stride) {
    float4 vv = ((const float4*)in)[i];
    __hip_bfloat16 h0 = __float2bfloat16(vv.x);
    __hip_bfloat16 h1 = __float2bfloat16(vv.y);
    __hip_bfloat16 h2 = __float2bfloat16(vv.z);
    __hip_bfloat16 h3 = __float2bfloat16(vv.w);
    ushort4 o;
    o.x = *(unsigned short*)&h0;
    o.y = *(unsigned short*)&h1;
    o.z = *(unsigned short*)&h2;
    o.w = *(unsigned short*)&h3;
    ((ushort4*)out)[i] = o;
  }
}

// ---------------------------------------------------------------------------
// 256x256 tile, BK=64, fragment-pipelined GEMM (reads run UNDER MFMA).
// 8 waves (2M x 4N), per-wave 128x64, acc[8][4]; 2 barriers per K-tile.
// LDS 128KiB [dbuf2][A/B][half2][128x64] bf16, XOR-swizzled (R2-verified).
// ---------------------------------------------------------------------------
__global__ __launch_bounds__(512, 2) void gemm256_bn_relu(
    const __hip_bfloat16* __restrict__ A, long long a_hstride,
    const __hip_bfloat16* __restrict__ W,
    const float* __restrict__ gp, const float* __restrict__ bp,
    const float* __restrict__ mp, const float* __restrict__ vp,
    __hip_bfloat16* __restrict__ out)
{
  __shared__ __hip_bfloat16 sm[65536];   // 128 KiB

  const int tid  = threadIdx.x;
  const int w    = tid >> 6;
  const int lane = tid & 63;

  // XCD-bijective swizzle over 384 blocks (384 % 8 == 0)
  const int bid = blockIdx.x;
  const int swz = (bid & 7) * 48 + (bid >> 3);
  const int h   = swz >> 7;
  const int mt  = (swz & 127) >> 3;
  const int nt  = swz & 7;

  const __hip_bfloat16* Abase = A + (size_t)h * (size_t)a_hstride + (size_t)(mt * 256) * CDIM;
  const __hip_bfloat16* Bbase = W + ((size_t)h * CDIM + (size_t)(nt * 256)) * CDIM;

  const int slot0 = w * 128 + lane;
  const int srow  = slot0 >> 3;
  const int gcol  = ((slot0 & 7) ^ (srow & 7)) << 3;

  const int wm = w >> 2;
  const int wn = w & 3;
  const int fr = lane & 15;
  const int fg = lane >> 4;
  const int offs0 = fr * 64 + ((fg ^ (fr & 7)) << 3);        // ksub 0
  const int offs1 = fr * 64 + (((fg + 4) ^ (fr & 7)) << 3);  // ksub 1
  const int aOff = wm * 8192;
  const int bOff = 16384 + (wn >> 1) * 8192 + (wn & 1) * 4096;

  auto STAGE = [&](int dbuf, int mat, int ih, int t) {
    const __hip_bfloat16* sp = (mat ? Bbase : Abase)
        + (size_t)(ih * 128 + srow) * CDIM + t * 64 + gcol;
    __hip_bfloat16* dp = &sm[dbuf * 32768 + mat * 16384 + ih * 8192 + w * 1024];
    gload_lds16(sp, dp);
    gload_lds16(sp + 8 * CDIM, dp + 512);
  };

  f32x4 acc[8][4] = {};
  short8 A0[4], A1[4], B0[2], B1[2];

  const __hip_bfloat16* aB[2] = { &sm[aOff], &sm[32768 + aOff] };
  const __hip_bfloat16* bB[2] = { &sm[bOff], &sm[32768 + bOff] };

#define LDA(dst, base, i0, offs)                                        \
  _Pragma("unroll") for (int i_ = 0; i_ < 4; ++i_)                      \
    dst[i_] = *(const short8*)((base) + ((i0) + i_) * 1024 + (offs));
#define LDB(dst, base, j0, offs)                                        \
  _Pragma("unroll") for (int j_ = 0; j_ < 2; ++j_)                      \
    dst[j_] = *(const short8*)((base) + ((j0) + j_) * 1024 + (offs));

#define MFMA_Q(ioff, joff, Aset, Bset)                                  \
  __builtin_amdgcn_s_setprio(1);                                        \
  _Pragma("unroll") for (int i_ = 0; i_ < 4; ++i_)                      \
  _Pragma("unroll") for (int j_ = 0; j_ < 2; ++j_)                      \
    acc[i_ + ioff][j_ + joff] = __builtin_amdgcn_mfma_f32_16x16x32_bf16( \
        Aset[i_], Bset[j_], acc[i_ + ioff][j_ + joff], 0, 0, 0);        \
  __builtin_amdgcn_s_setprio(0);

  // ---- prologue ----
  STAGE(0, 0, 0, 0); STAGE(0, 0, 1, 0); STAGE(0, 1, 0, 0); STAGE(0, 1, 1, 0);
  STAGE(1, 0, 0, 1);
  asm volatile("s_waitcnt vmcnt(2)" ::: "memory");
  SB();
  __builtin_amdgcn_s_barrier();
  SB();
  LDA(A0, aB[0], 0, offs0);
  LDA(A1, aB[0], 4, offs0);
  LDB(B0, bB[0], 0, offs0);
  LDB(B1, bB[0], 2, offs0);
  SB();

#pragma unroll 2
  for (int t = 0; t < NKT - 1; ++t) {
    const int d = t & 1, dn = d ^ 1;
    const __hip_bfloat16* aHd = aB[d];
    const __hip_bfloat16* bHd = bB[d];
    const __hip_bfloat16* aHn = aB[dn];
    const __hip_bfloat16* bHn = bB[dn];

    MFMA_Q(0, 0, A0, B0); SB();
    STAGE(dn, 0, 1, t + 1); SB();
    MFMA_Q(0, 2, A0, B1); SB();
    LDA(A0, aHd, 0, offs1); SB();
    MFMA_Q(4, 0, A1, B0); SB();
    STAGE(dn, 1, 0, t + 1);
    LDB(B0, bHd, 0, offs1); SB();
    MFMA_Q(4, 2, A1, B1); SB();
    STAGE(dn, 1, 1, t + 1);
    LDB(B1, bHd, 2, offs1);
    LDA(A1, aHd, 4, offs1); SB();
    MFMA_Q(0, 0, A0, B0); SB();
    if (t + 2 < NKT) { STAGE(d, 0, 0, t + 2); }
    SB();
    MFMA_Q(0, 2, A0, B1); SB();
    if (t + 2 < NKT) { asm volatile("s_waitcnt vmcnt(6)" ::: "memory"); }
    else             { asm volatile("s_waitcnt vmcnt(4)" ::: "memory"); }
    SB();
    __builtin_amdgcn_s_barrier();
    SB();
    LDA(A0, aHn, 0, offs0); SB();
    MFMA_Q(4, 0, A1, B0); SB();
    if (t + 2 < NKT) { asm volatile("s_waitcnt vmcnt(2)" ::: "memory"); }
    else             { asm volatile("s_waitcnt vmcnt(0)" ::: "memory"); }
    SB();
    __builtin_amdgcn_s_barrier();
    SB();
    LDB(B0, bHn, 0, offs0); SB();
    MFMA_Q(4, 2, A1, B1); SB();
    LDB(B1, bHn, 2, offs0);
    LDA(A1, aHn, 4, offs0); SB();
  }

  // ---- peeled last tile ----
  {
    const int d = (NKT - 1) & 1;
    const __hip_bfloat16* aHd = aB[d];
    const __hip_bfloat16* bHd = bB[d];
    MFMA_Q(0, 0, A0, B0); SB();
    MFMA_Q(0, 2, A0, B1); SB();
    LDA(A0, aHd, 0, offs1); SB();
    MFMA_Q(4, 0, A1, B0); SB();
    LDB(B0, bHd, 0, offs1); SB();
    MFMA_Q(4, 2, A1, B1); SB();
    LDB(B1, bHd, 2, offs1);
    LDA(A1, aHd, 4, offs1); SB();
    MFMA_Q(0, 0, A0, B0); SB();
    MFMA_Q(0, 2, A0, B1); SB();
    MFMA_Q(4, 0, A1, B0); SB();
    MFMA_Q(4, 2, A1, B1); SB();
  }

  // epilogue: BN (folded) + ReLU, bf16 store.
  const float* gh = gp + h * CDIM;
  const float* bh = bp + h * CDIM;
  const float* mh = mp + h * CDIM;
  const float* vh = vp + h * CDIM;
  const int colBase = nt * 256 + wn * 64 + fr;
  const int rowBase = mt * 256 + wm * 128 + fg * 4;
#pragma unroll
  for (int j = 0; j < 4; ++j) {
    const int col = colBase + j * 16;
    const float sc = gh[col] / sqrtf(vh[col] + BN_EPS);
    const float sh = bh[col] - mh[col] * sc;
#pragma unroll
    for (int i = 0; i < 8; ++i) {
      const int row = rowBase + i * 16;
#pragma unroll
      for (int rr = 0; rr < 4; ++rr) {
        float val = acc[i][j][rr] * sc + sh;
        val = val > 0.f ? val : 0.f;
        out[((size_t)h * MROWS + row + rr) * CDIM + col] = __float2bfloat16(val);
      }
    }
  }
}

// ---------------------------------------------------------------------------
// Pack final-layer weights into bf16 Wfb[3][16][2048], zero-padded.
// ---------------------------------------------------------------------------
__global__ __launch_bounds__(256) void pack_wf(
    const float* __restrict__ Wf0, const float* __restrict__ Wf1,
    const float* __restrict__ Wf2, __hip_bfloat16* __restrict__ Wfb) {
  int idx = blockIdx.x * 256 + threadIdx.x;   // 3*16*2048 = 98304
  if (idx >= 3 * 16 * CDIM) return;
  int h = idx / (16 * CDIM);
  int rem = idx - h * 16 * CDIM;
  int j = rem / CDIM;
  int k = rem - j * CDIM;
  float v = 0.f;
  if (h == 0)            v = Wf0[j * CDIM + k];
  else if (h == 1)       { if (j < 5) v = Wf1[j * CDIM + k]; }
  else                   { if (j < 5) v = Wf2[j * CDIM + k]; }
  Wfb[idx] = __float2bfloat16(v);
}

// ---------------------------------------------------------------------------
// Final 1x1 convs via MFMA, K-split 8 ways across waves.
// Block = 512 thr (8 waves), owns 16 rows. Wave w: k in [w*256, w*256+256).
// Per k-step, per head: A-frag = act rows (row=lane&15, k=(lane>>4)*8),
// B-frag = Wfb rows (col=lane&15). Partials reduced through LDS.
// ---------------------------------------------------------------------------
__global__ __launch_bounds__(512) void final_mfma(
    const __hip_bfloat16* __restrict__ act,   // [3][4096][2048]
    const __hip_bfloat16* __restrict__ Wfb,   // [3][16][2048]
    const float* __restrict__ bf0, const float* __restrict__ bf1,
    const float* __restrict__ bf2, float* __restrict__ out)  // [4096][26]
{
  __shared__ float red[8][3][256];
  const int tid  = threadIdx.x;
  const int w    = tid >> 6;
  const int lane = tid & 63;
  const int r0   = blockIdx.x * 16;
  const int fr   = lane & 15;
  const int fk   = (lane >> 4) * 8;
  const int kbase = w * 256 + fk;

  f32x4 acc[3] = {};
  const __hip_bfloat16* aRow = act + (size_t)(r0 + fr) * CDIM + kbase;
  const __hip_bfloat16* bRow = Wfb + (size_t)fr * CDIM + kbase;
#pragma unroll
  for (int ks = 0; ks < 8; ++ks) {
    const int k = ks * 32;
#pragma unroll
    for (int h = 0; h < 3; ++h) {
      short8 a = *(const short8*)(aRow + (size_t)h * MROWS * CDIM + k);
      short8 b = *(const short8*)(bRow + h * 16 * CDIM + k);
      acc[h] = __builtin_amdgcn_mfma_f32_16x16x32_bf16(a, b, acc[h], 0, 0, 0);
    }
  }

  const int rb = (lane >> 4) * 4;
#pragma unroll
  for (int h = 0; h < 3; ++h)
#pragma unroll
    for (int r = 0; r < 4; ++r)
      red[w][h][(rb + r) * 16 + fr] = acc[h][r];
  __syncthreads();

  for (int e = tid; e < 768; e += 512) {
    const int h = e >> 8, idx = e & 255;
    const int row = idx >> 4, col = idx & 15;
    float s = 0.f;
#pragma unroll
    for (int w2 = 0; w2 < 8; ++w2) s += red[w2][h][idx];
    float* orow = out + (size_t)(r0 + row) * 26;
    if (h == 0)                 orow[col]      = s + bf0[col];
    else if (h == 1) { if (col < 5) orow[16 + col] = s + bf1[col]; }
    else             { if (col < 5) orow[21 + col] = s + bf2[col]; }
  }
}

// ---------------------------------------------------------------------------
extern "C" void kernel_launch(void* const* d_in, const int* in_sizes, int n_in,
                              void* d_out, int out_size, void* d_ws, size_t ws_size,
                              hipStream_t stream) {
  const float* feat = (const float*)d_in[0];
  const float* W1 = (const float*)d_in[1];
  const float* g1 = (const float*)d_in[2];
  const float* b1 = (const float*)d_in[3];
  const float* m1 = (const float*)d_in[4];
  const float* v1 = (const float*)d_in[5];
  const float* W2 = (const float*)d_in[6];
  const float* g2 = (const float*)d_in[7];
  const float* b2 = (const float*)d_in[8];
  const float* m2 = (const float*)d_in[9];
  const float* v2 = (const float*)d_in[10];
  const float* W3 = (const float*)d_in[11];
  const float* g3 = (const float*)d_in[12];
  const float* b3 = (const float*)d_in[13];
  const float* m3 = (const float*)d_in[14];
  const float* v3 = (const float*)d_in[15];
  const float* Wf0 = (const float*)d_in[16];
  const float* bf0 = (const float*)d_in[17];
  const float* Wf1 = (const float*)d_in[18];
  const float* bf1 = (const float*)d_in[19];
  const float* Wf2 = (const float*)d_in[20];
  const float* bf2 = (const float*)d_in[21];
  float* out = (float*)d_out;

  // workspace: wbuf 24MB | actA 48MB | actB 48MB (features bf16 overlaps actB)
  // Wfb (192KB) reuses wbuf after gemm3 has consumed W3.
  char* ws = (char*)d_ws;
  __hip_bfloat16* wbuf = (__hip_bfloat16*)ws;
  __hip_bfloat16* actA = (__hip_bfloat16*)(ws + 25165824);
  __hip_bfloat16* actB = (__hip_bfloat16*)(ws + 25165824 + 50331648);
  __hip_bfloat16* xb   = actB;
  __hip_bfloat16* Wfb  = wbuf;

  const int nW4 = (3 * CDIM * CDIM) / 4;
  const int nX4 = (MROWS * CDIM) / 4;
  const long long hstride = (long long)MROWS * CDIM;

  cvt_f32_bf16<<<2048, 256, 0, stream>>>(feat, (unsigned short*)xb, nX4);

  cvt_f32_bf16<<<2048, 256, 0, stream>>>(W1, (unsigned short*)wbuf, nW4);
  gemm256_bn_relu<<<384, 512, 0, stream>>>(xb, 0LL, wbuf, g1, b1, m1, v1, actA);

  cvt_f32_bf16<<<2048, 256, 0, stream>>>(W2, (unsigned short*)wbuf, nW4);
  gemm256_bn_relu<<<384, 512, 0, stream>>>(actA, hstride, wbuf, g2, b2, m2, v2, actB);

  cvt_f32_bf16<<<2048, 256, 0, stream>>>(W3, (unsigned short*)wbuf, nW4);
  gemm256_bn_relu<<<384, 512, 0, stream>>>(actB, hstride, wbuf, g3, b3, m3, v3, actA);

  pack_wf<<<384, 256, 0, stream>>>(Wf0, Wf1, Wf2, Wfb);
  final_mfma<<<256, 512, 0, stream>>>(actA, Wfb, bf0, bf1, bf2, out);
}